// Round 1
// baseline (1659.736 us; speedup 1.0000x reference)
//
#include <hip/hip_runtime.h>

#define SEQ   2048
#define BATCH 2
#define EMB   512
#define NH    8
#define HD    64
#define MTOK  (SEQ*BATCH)   // 4096
#define MAXS  256           // compact sparse-support list capacity per row

// =====================================================================
// GEMM1: X(4096x512) @ W[z](512x512)^T + b  -> LayerNorm per 64-chunk
//        -> (q only) * D^-0.5 -> write in attention layout [b*H+h][i][d]
// grid (32, 8, 3)  block 256
// =====================================================================
__global__ __launch_bounds__(256) void gemm_qkv_ln(
    const float* __restrict__ query, const float* __restrict__ key_in,
    const float* __restrict__ value,
    const float* __restrict__ ipw, const float* __restrict__ ipb,
    float* __restrict__ qn, float* __restrict__ kn, float* __restrict__ vn)
{
    const int z = blockIdx.z;
    const float* X = (z == 0) ? query : (z == 1) ? key_in : value;
    float* dst     = (z == 0) ? qn    : (z == 1) ? kn     : vn;
    const float scale = (z == 0) ? 0.125f : 1.0f;   // D^-0.5 = 64^-0.5

    const int t0  = blockIdx.x * 128;      // token tile
    const int h   = blockIdx.y;            // head == 64-feature tile
    const int og0 = z * EMB + h * 64;      // row offset into in_proj_weight

    __shared__ float Xs[16][132];          // [c][t], stride 132 (33*16B aligned)
    __shared__ float Ws[16][68];           // [c][o], stride 68  (17*16B aligned)
    __shared__ float Et[128][68];          // epilogue tile
    __shared__ float mu_s[128], rs_s[128];

    const int tid = threadIdx.x;
    const int tx  = tid & 15;              // o-tile (4 cols)
    const int ty  = tid >> 4;              // t-tile (8 rows)

    float acc[8][4];
#pragma unroll
    for (int i = 0; i < 8; ++i)
#pragma unroll
        for (int j = 0; j < 4; ++j) acc[i][j] = 0.f;

    for (int ck = 0; ck < 32; ++ck) {
        const int c0 = ck * 16;
        // X tile: 128 t x 16 c  (512 float4, 2 per thread), transpose into [c][t]
#pragma unroll
        for (int p = 0; p < 2; ++p) {
            int f  = tid + p * 256;
            int tl = f >> 2, cq = (f & 3) << 2;
            const float4 v = *(const float4*)&X[(size_t)(t0 + tl) * EMB + c0 + cq];
            Xs[cq + 0][tl] = v.x; Xs[cq + 1][tl] = v.y;
            Xs[cq + 2][tl] = v.z; Xs[cq + 3][tl] = v.w;
        }
        // W tile: 64 o x 16 c (256 float4, 1 per thread)
        {
            int f  = tid;
            int ol = f >> 2, cq = (f & 3) << 2;
            const float4 v = *(const float4*)&ipw[(size_t)(og0 + ol) * EMB + c0 + cq];
            Ws[cq + 0][ol] = v.x; Ws[cq + 1][ol] = v.y;
            Ws[cq + 2][ol] = v.z; Ws[cq + 3][ol] = v.w;
        }
        __syncthreads();
#pragma unroll
        for (int c = 0; c < 16; ++c) {
            const float4 a0 = *(const float4*)&Xs[c][ty * 8];
            const float4 a1 = *(const float4*)&Xs[c][ty * 8 + 4];
            const float4 b  = *(const float4*)&Ws[c][tx * 4];
            const float av[8] = {a0.x, a0.y, a0.z, a0.w, a1.x, a1.y, a1.z, a1.w};
            const float bv[4] = {b.x, b.y, b.z, b.w};
#pragma unroll
            for (int i = 0; i < 8; ++i)
#pragma unroll
                for (int j = 0; j < 4; ++j) acc[i][j] += av[i] * bv[j];
        }
        __syncthreads();
    }

    // ---- epilogue: + bias, stage, LayerNorm per token over the 64 cols ----
#pragma unroll
    for (int j = 0; j < 4; ++j) {
        const float bj = ipb[og0 + tx * 4 + j];
#pragma unroll
        for (int i = 0; i < 8; ++i) Et[ty * 8 + i][tx * 4 + j] = acc[i][j] + bj;
    }
    __syncthreads();
    if (tid < 128) {
        float s = 0.f;
#pragma unroll
        for (int dq = 0; dq < 64; dq += 4) {
            const float4 v = *(const float4*)&Et[tid][dq];
            s += v.x + v.y + v.z + v.w;
        }
        const float mu = s * (1.0f / 64.0f);
        float vs = 0.f;
#pragma unroll
        for (int dq = 0; dq < 64; dq += 4) {
            const float4 v = *(const float4*)&Et[tid][dq];
            const float a = v.x - mu, b = v.y - mu, c = v.z - mu, d = v.w - mu;
            vs += a * a + b * b + c * c + d * d;
        }
        mu_s[tid] = mu;
        rs_s[tid] = rsqrtf(vs * (1.0f / 64.0f) + 1e-5f);
    }
    __syncthreads();
    // write out in [b*NH+h][i][d] layout; t_global = i*BATCH + b
#pragma unroll
    for (int p = 0; p < 8; ++p) {
        int f  = tid + p * 256;            // 2048 float4 total
        int tl = f >> 4, dq = (f & 15) << 2;
        const float4 v = *(const float4*)&Et[tl][dq];
        const float mu = mu_s[tl];
        const float rs = rs_s[tl] * scale;
        float4 o;
        o.x = (v.x - mu) * rs; o.y = (v.y - mu) * rs;
        o.z = (v.z - mu) * rs; o.w = (v.w - mu) * rs;
        const int tg = t0 + tl;
        const int ii = tg >> 1;            // i  (BATCH==2)
        const int b  = tg & 1;             // b
        const size_t base = ((size_t)(b * NH + h) * SEQ + ii) * 64 + dq;
        *(float4*)&dst[base] = o;
    }
}

// =====================================================================
// Attention with sparsemax. grid (SEQ/4, BATCH*NH) block 256 (4 waves).
// wave = one query row. scores in 32 VGPRs (j = tile*64 + lane).
// =====================================================================
__global__ __launch_bounds__(256) void attn_sparsemax(
    const float* __restrict__ qn, const float* __restrict__ kn,
    const float* __restrict__ vn, float* __restrict__ attn_out)
{
    __shared__ float Kt[64][68];                   // K tile [j][d], pad 68
    __shared__ float plist[4][MAXS];
    __shared__ unsigned short jlist[4][MAXS];

    const int tid  = threadIdx.x;
    const int w    = tid >> 6;
    const int lane = tid & 63;
    const int bh   = blockIdx.y;
    const int i    = blockIdx.x * 4 + w;

    const size_t bh_base = (size_t)bh * SEQ * 64;
    const float* qrow = qn + bh_base + (size_t)i * 64;
    const float* kb   = kn + bh_base;
    const float* vb   = vn + bh_base;

    // q row in registers (wave-uniform values)
    float qv[64];
#pragma unroll
    for (int dq = 0; dq < 64; dq += 4) {
        const float4 v = *(const float4*)&qrow[dq];
        qv[dq] = v.x; qv[dq + 1] = v.y; qv[dq + 2] = v.z; qv[dq + 3] = v.w;
    }

    // ---------------- scores: z[t] for j = t*64 + lane ----------------
    float z[32];
#pragma unroll
    for (int tile = 0; tile < 32; ++tile) {
        __syncthreads();
#pragma unroll
        for (int p = 0; p < 4; ++p) {
            int f  = tid + p * 256;                // 1024 float4
            int jl = f >> 4, dq = (f & 15) << 2;
            const float4 v = *(const float4*)&kb[(size_t)(tile * 64 + jl) * 64 + dq];
            *(float4*)&Kt[jl][dq] = v;
        }
        __syncthreads();
        float a = 0.f;
#pragma unroll
        for (int dq = 0; dq < 64; dq += 4) {
            const float4 k4 = *(const float4*)&Kt[lane][dq];
            a += qv[dq] * k4.x + qv[dq + 1] * k4.y + qv[dq + 2] * k4.z + qv[dq + 3] * k4.w;
        }
        z[tile] = a;
    }

    // ---------------- sparsemax via Michelot fixed point ----------------
    // tau* >= max(z) - 1, so S0 = {z > max-1} contains the true support.
    float m = z[0];
#pragma unroll
    for (int t = 1; t < 32; ++t) m = fmaxf(m, z[t]);
#pragma unroll
    for (int d = 32; d >= 1; d >>= 1) m = fmaxf(m, __shfl_xor(m, d));

    float tau = m - 1.0f;
    int cprev = -1;
    for (int it = 0; it < 48; ++it) {
        float s = 0.f, c = 0.f;
#pragma unroll
        for (int t = 0; t < 32; ++t) {
            if (z[t] > tau) { s += z[t]; c += 1.0f; }
        }
#pragma unroll
        for (int d = 32; d >= 1; d >>= 1) {
            s += __shfl_xor(s, d);
            c += __shfl_xor(c, d);
        }
        s = __shfl(s, 0);                  // make tau bit-identical on all lanes
        c = __shfl(c, 0);
        tau = (s - 1.0f) / c;
        const int ci = (int)c;
        if (ci == cprev) break;            // support stable -> converged (exact)
        cprev = ci;
    }

#pragma unroll
    for (int t = 0; t < 32; ++t) z[t] = fmaxf(z[t] - tau, 0.f);

    // ------------- compact sparse support list (ballot + popc) -------------
    int myk = 0;                            // wave-uniform
#pragma unroll
    for (int t = 0; t < 32; ++t) {
        const unsigned long long mask = __ballot(z[t] > 0.f);
        const int pos = myk + (int)__popcll(mask & ((1ull << lane) - 1ull));
        if (z[t] > 0.f && pos < MAXS) {
            jlist[w][pos] = (unsigned short)(t * 64 + lane);
            plist[w][pos] = z[t];
        }
        myk += (int)__popcll(mask);
    }
    __syncthreads();

    // ---------------- P @ V : only touch support rows of V ----------------
    float acc = 0.f;
    if (myk <= MAXS) {
        for (int e = 0; e < myk; ++e) {
            const int   j  = jlist[w][e];
            const float pj = plist[w][e];
            acc += pj * vb[(size_t)j * 64 + lane];
        }
    } else {                                // fallback: full scan via shfl
#pragma unroll 1
        for (int t = 0; t < 32; ++t) {
            const float pt = z[t];
            for (int jl = 0; jl < 64; ++jl) {
                const float pj = __shfl(pt, jl);
                if (pj > 0.f) acc += pj * vb[(size_t)(t * 64 + jl) * 64 + lane];
            }
        }
    }

    const int b = bh >> 3, h = bh & 7;
    attn_out[(size_t)(i * BATCH + b) * EMB + h * 64 + lane] = acc;
}

// =====================================================================
// GEMM2: attn_out(4096x512) @ out_proj_weight(512x512)^T + bias -> d_out
// grid (32, 8)  block 256
// =====================================================================
__global__ __launch_bounds__(256) void gemm_out_proj(
    const float* __restrict__ X, const float* __restrict__ W,
    const float* __restrict__ bias, float* __restrict__ out)
{
    const int t0 = blockIdx.x * 128;
    const int o0 = blockIdx.y * 64;

    __shared__ float Xs[16][132];
    __shared__ float Ws[16][68];

    const int tid = threadIdx.x;
    const int tx  = tid & 15;
    const int ty  = tid >> 4;

    float acc[8][4];
#pragma unroll
    for (int i = 0; i < 8; ++i)
#pragma unroll
        for (int j = 0; j < 4; ++j) acc[i][j] = 0.f;

    for (int ck = 0; ck < 32; ++ck) {
        const int c0 = ck * 16;
#pragma unroll
        for (int p = 0; p < 2; ++p) {
            int f  = tid + p * 256;
            int tl = f >> 2, cq = (f & 3) << 2;
            const float4 v = *(const float4*)&X[(size_t)(t0 + tl) * EMB + c0 + cq];
            Xs[cq + 0][tl] = v.x; Xs[cq + 1][tl] = v.y;
            Xs[cq + 2][tl] = v.z; Xs[cq + 3][tl] = v.w;
        }
        {
            int f  = tid;
            int ol = f >> 2, cq = (f & 3) << 2;
            const float4 v = *(const float4*)&W[(size_t)(o0 + ol) * EMB + c0 + cq];
            Ws[cq + 0][ol] = v.x; Ws[cq + 1][ol] = v.y;
            Ws[cq + 2][ol] = v.z; Ws[cq + 3][ol] = v.w;
        }
        __syncthreads();
#pragma unroll
        for (int c = 0; c < 16; ++c) {
            const float4 a0 = *(const float4*)&Xs[c][ty * 8];
            const float4 a1 = *(const float4*)&Xs[c][ty * 8 + 4];
            const float4 b  = *(const float4*)&Ws[c][tx * 4];
            const float av[8] = {a0.x, a0.y, a0.z, a0.w, a1.x, a1.y, a1.z, a1.w};
            const float bv[4] = {b.x, b.y, b.z, b.w};
#pragma unroll
            for (int i = 0; i < 8; ++i)
#pragma unroll
                for (int j = 0; j < 4; ++j) acc[i][j] += av[i] * bv[j];
        }
        __syncthreads();
    }

    const float b0 = bias[o0 + tx * 4 + 0];
    const float b1 = bias[o0 + tx * 4 + 1];
    const float b2 = bias[o0 + tx * 4 + 2];
    const float b3 = bias[o0 + tx * 4 + 3];
#pragma unroll
    for (int i = 0; i < 8; ++i) {
        float4 o;
        o.x = acc[i][0] + b0; o.y = acc[i][1] + b1;
        o.z = acc[i][2] + b2; o.w = acc[i][3] + b3;
        *(float4*)&out[(size_t)(t0 + ty * 8 + i) * EMB + o0 + tx * 4] = o;
    }
}

// =====================================================================
extern "C" void kernel_launch(void* const* d_in, const int* in_sizes, int n_in,
                              void* d_out, int out_size, void* d_ws, size_t ws_size,
                              hipStream_t stream)
{
    const float* query = (const float*)d_in[0];
    const float* key_  = (const float*)d_in[1];
    const float* value = (const float*)d_in[2];
    const float* ipw   = (const float*)d_in[3];
    const float* ipb   = (const float*)d_in[4];
    const float* opw   = (const float*)d_in[5];
    const float* opb   = (const float*)d_in[6];
    // d_in[7] = update_steps_max (0) -> single attention pass, unused

    float* ws = (float*)d_ws;
    float* qn = ws;                       // [16][2048][64]  (2,097,152 f)
    float* kn = ws + 2097152;             // [16][2048][64]
    float* vn = ws + 4194304;             // [16][2048][64]
    float* ao = ws + 6291456;             // [4096][512]
    float* out = (float*)d_out;

    gemm_qkv_ln   <<<dim3(32, 8, 3),  256, 0, stream>>>(query, key_, value, ipw, ipb, qn, kn, vn);
    attn_sparsemax<<<dim3(SEQ / 4, BATCH * NH), 256, 0, stream>>>(qn, kn, vn, ao);
    gemm_out_proj <<<dim3(32, 8),     256, 0, stream>>>(ao, opw, opb, out);
}

// Round 2
// 444.473 us; speedup vs baseline: 3.7342x; 3.7342x over previous
//
#include <hip/hip_runtime.h>

#define SEQ   2048
#define BATCH 2
#define EMB   512
#define NH    8
#define HD    64
#define CAP   48          // compact-list capacity per (row, wave); overflow -> atomic path

typedef short bf16x8 __attribute__((ext_vector_type(8)));
typedef float f32x4  __attribute__((ext_vector_type(4)));

static __device__ __forceinline__ unsigned short f2bf(float f) {
    unsigned u = __float_as_uint(f);
    unsigned r = (u + 0x7FFF + ((u >> 16) & 1)) >> 16;   // round-to-nearest-even
    return (unsigned short)r;
}
static __device__ __forceinline__ float bf2f(unsigned short h) {
    return __uint_as_float((unsigned)h << 16);
}

// =====================================================================
// GEMM1: X(4096x512) @ W[z](512x512)^T + b -> LayerNorm per 64-chunk
//   z=0: Q -> *D^-0.5 -> split bf16 hi/lo   [bh][i][d]
//   z=1: K ->          split bf16 hi/lo     [bh][i][d]
//   z=2: V -> f32                           [bh][i][d]
// grid (32, 8, 3)  block 256
// =====================================================================
__global__ __launch_bounds__(256) void gemm_qkv_ln(
    const float* __restrict__ query, const float* __restrict__ key_in,
    const float* __restrict__ value,
    const float* __restrict__ ipw, const float* __restrict__ ipb,
    unsigned short* __restrict__ qhi, unsigned short* __restrict__ qlo,
    unsigned short* __restrict__ khi, unsigned short* __restrict__ klo,
    float* __restrict__ vn)
{
    const int z = blockIdx.z;
    const float* X = (z == 0) ? query : (z == 1) ? key_in : value;
    unsigned short* dh = (z == 0) ? qhi : khi;
    unsigned short* dl = (z == 0) ? qlo : klo;
    const float scale = (z == 0) ? 0.125f : 1.0f;   // D^-0.5 = 64^-0.5

    const int t0  = blockIdx.x * 128;
    const int h   = blockIdx.y;
    const int og0 = z * EMB + h * 64;

    __shared__ float Xs[16][132];
    __shared__ float Ws[16][68];
    __shared__ float Et[128][68];
    __shared__ float mu_s[128], rs_s[128];

    const int tid = threadIdx.x;
    const int tx  = tid & 15;
    const int ty  = tid >> 4;

    float acc[8][4];
#pragma unroll
    for (int i = 0; i < 8; ++i)
#pragma unroll
        for (int j = 0; j < 4; ++j) acc[i][j] = 0.f;

    for (int ck = 0; ck < 32; ++ck) {
        const int c0 = ck * 16;
#pragma unroll
        for (int p = 0; p < 2; ++p) {
            int f  = tid + p * 256;
            int tl = f >> 2, cq = (f & 3) << 2;
            const float4 v = *(const float4*)&X[(size_t)(t0 + tl) * EMB + c0 + cq];
            Xs[cq + 0][tl] = v.x; Xs[cq + 1][tl] = v.y;
            Xs[cq + 2][tl] = v.z; Xs[cq + 3][tl] = v.w;
        }
        {
            int f  = tid;
            int ol = f >> 2, cq = (f & 3) << 2;
            const float4 v = *(const float4*)&ipw[(size_t)(og0 + ol) * EMB + c0 + cq];
            Ws[cq + 0][ol] = v.x; Ws[cq + 1][ol] = v.y;
            Ws[cq + 2][ol] = v.z; Ws[cq + 3][ol] = v.w;
        }
        __syncthreads();
#pragma unroll
        for (int c = 0; c < 16; ++c) {
            const float4 a0 = *(const float4*)&Xs[c][ty * 8];
            const float4 a1 = *(const float4*)&Xs[c][ty * 8 + 4];
            const float4 b  = *(const float4*)&Ws[c][tx * 4];
            const float av[8] = {a0.x, a0.y, a0.z, a0.w, a1.x, a1.y, a1.z, a1.w};
            const float bv[4] = {b.x, b.y, b.z, b.w};
#pragma unroll
            for (int i = 0; i < 8; ++i)
#pragma unroll
                for (int j = 0; j < 4; ++j) acc[i][j] += av[i] * bv[j];
        }
        __syncthreads();
    }

#pragma unroll
    for (int j = 0; j < 4; ++j) {
        const float bj = ipb[og0 + tx * 4 + j];
#pragma unroll
        for (int i = 0; i < 8; ++i) Et[ty * 8 + i][tx * 4 + j] = acc[i][j] + bj;
    }
    __syncthreads();
    if (tid < 128) {
        float s = 0.f;
#pragma unroll
        for (int dq = 0; dq < 64; dq += 4) {
            const float4 v = *(const float4*)&Et[tid][dq];
            s += v.x + v.y + v.z + v.w;
        }
        const float mu = s * (1.0f / 64.0f);
        float vs = 0.f;
#pragma unroll
        for (int dq = 0; dq < 64; dq += 4) {
            const float4 v = *(const float4*)&Et[tid][dq];
            const float a = v.x - mu, b = v.y - mu, c = v.z - mu, d = v.w - mu;
            vs += a * a + b * b + c * c + d * d;
        }
        mu_s[tid] = mu;
        rs_s[tid] = rsqrtf(vs * (1.0f / 64.0f) + 1e-5f);
    }
    __syncthreads();
#pragma unroll
    for (int p = 0; p < 8; ++p) {
        int f  = tid + p * 256;
        int tl = f >> 4, dq = (f & 15) << 2;
        const float4 v = *(const float4*)&Et[tl][dq];
        const float mu = mu_s[tl];
        const float rs = rs_s[tl] * scale;
        float x0 = (v.x - mu) * rs, x1 = (v.y - mu) * rs;
        float x2 = (v.z - mu) * rs, x3 = (v.w - mu) * rs;
        const int tg = t0 + tl;
        const int ii = tg >> 1;
        const int b  = tg & 1;
        const size_t base = ((size_t)(b * NH + h) * SEQ + ii) * 64 + dq;
        if (z == 2) {
            float4 o; o.x = x0; o.y = x1; o.z = x2; o.w = x3;
            *(float4*)&vn[base] = o;
        } else {
            ushort4 hi, lo;
            hi.x = f2bf(x0); lo.x = f2bf(x0 - bf2f(hi.x));
            hi.y = f2bf(x1); lo.y = f2bf(x1 - bf2f(hi.y));
            hi.z = f2bf(x2); lo.z = f2bf(x2 - bf2f(hi.z));
            hi.w = f2bf(x3); lo.w = f2bf(x3 - bf2f(hi.w));
            *(ushort4*)&dh[base] = hi;
            *(ushort4*)&dl[base] = lo;
        }
    }
}

// =====================================================================
// Fused attention: MFMA QK^T (split-bf16) -> Michelot sparsemax on
// register-resident scores -> sparse PV gather.
// grid (SEQ/16, BATCH*NH)  block 512 (8 waves).
// Block = 16 q-rows; wave w owns key-cols [w*256, w*256+256).
// Fragment layout (mfma_f32_16x16x32_bf16, verified):
//   A: row=lane&15, k=(lane>>4)*8+j ; B: col=lane&15, same k
//   C: col=lane&15, row=(lane>>4)*4+reg
// =====================================================================
__global__ __launch_bounds__(512, 4) void attn_sparsemax_mfma(
    const unsigned short* __restrict__ qhi, const unsigned short* __restrict__ qlo,
    const unsigned short* __restrict__ khi, const unsigned short* __restrict__ klo,
    const float* __restrict__ vn, float* __restrict__ ao)
{
    __shared__ float          plist[16][8][CAP];
    __shared__ unsigned short jlist[16][8][CAP];
    __shared__ short          lcnt[16][8];
    __shared__ float          wred[8][16];     // per-wave partial max / sum
    __shared__ float          wcnt[8][16];     // per-wave partial count
    __shared__ float          O_lds[16][64];   // overflow accumulator

    const int tid = threadIdx.x;
    const int w   = tid >> 6;
    const int l   = tid & 63;
    const int c   = l & 15;         // col-within-fragment / A-row provider
    const int g   = l >> 4;         // k-group; C rows g*4..g*4+3
    const int bh  = blockIdx.y;
    const int q0  = blockIdx.x * 16;

    const size_t bhoff = (size_t)bh * SEQ * 64;
    const unsigned short* qh = qhi + bhoff;
    const unsigned short* ql = qlo + bhoff;
    const unsigned short* kh = khi + bhoff;
    const unsigned short* kl = klo + bhoff;
    const float*          vb = vn  + bhoff;

    // zero overflow accumulator (visible after first barrier)
    for (int f = tid; f < 16 * 64; f += 512) ((float*)O_lds)[f] = 0.f;

    // ---- A fragments (Q rows q0..q0+15), loaded once ----
    const size_t qrow = (size_t)(q0 + c) * 64 + g * 8;
    const bf16x8 ah0 = *(const bf16x8*)&qh[qrow];
    const bf16x8 ah1 = *(const bf16x8*)&qh[qrow + 32];
    const bf16x8 al0 = *(const bf16x8*)&ql[qrow];
    const bf16x8 al1 = *(const bf16x8*)&ql[qrow + 32];

    // ---- scores: 16 fragments x (hi*hi k0,k1 + lo*hi + hi*lo) ----
    f32x4 acc[16];
#pragma unroll
    for (int nf = 0; nf < 16; ++nf) acc[nf] = (f32x4){0.f, 0.f, 0.f, 0.f};

    const int n0base = w * 256;
#pragma unroll
    for (int nf = 0; nf < 16; ++nf) {
        const size_t krow = (size_t)(n0base + nf * 16 + c) * 64 + g * 8;
        f32x4 t = acc[nf];
        const bf16x8 bh0 = *(const bf16x8*)&kh[krow];
        t = __builtin_amdgcn_mfma_f32_16x16x32_bf16(ah0, bh0, t, 0, 0, 0);
        t = __builtin_amdgcn_mfma_f32_16x16x32_bf16(al0, bh0, t, 0, 0, 0);
        const bf16x8 bh1 = *(const bf16x8*)&kh[krow + 32];
        t = __builtin_amdgcn_mfma_f32_16x16x32_bf16(ah1, bh1, t, 0, 0, 0);
        t = __builtin_amdgcn_mfma_f32_16x16x32_bf16(al1, bh1, t, 0, 0, 0);
        const bf16x8 bl0 = *(const bf16x8*)&kl[krow];
        t = __builtin_amdgcn_mfma_f32_16x16x32_bf16(ah0, bl0, t, 0, 0, 0);
        const bf16x8 bl1 = *(const bf16x8*)&kl[krow + 32];
        t = __builtin_amdgcn_mfma_f32_16x16x32_bf16(ah1, bl1, t, 0, 0, 0);
        acc[nf] = t;
    }

    // ---- row max (per lane: 4 rows g*4+j) ----
    float mj[4];
#pragma unroll
    for (int j = 0; j < 4; ++j) {
        float m = acc[0][j];
#pragma unroll
        for (int nf = 1; nf < 16; ++nf) m = fmaxf(m, acc[nf][j]);
#pragma unroll
        for (int d = 1; d <= 8; d <<= 1) m = fmaxf(m, __shfl_xor(m, d));
        mj[j] = m;
    }
    if (c == 0) {
#pragma unroll
        for (int j = 0; j < 4; ++j) wred[w][g * 4 + j] = mj[j];
    }
    __syncthreads();

    float tau[4];
    int   cprev[4];
#pragma unroll
    for (int j = 0; j < 4; ++j) {
        float m = wred[0][g * 4 + j];
#pragma unroll
        for (int ww = 1; ww < 8; ++ww) m = fmaxf(m, wred[ww][g * 4 + j]);
        tau[j]   = m - 1.0f;          // tau* >= max-1  =>  S0 superset of support
        cprev[j] = -1;
    }

    // ---- Michelot fixed point (2 barriers / iter, __any convergence) ----
    for (int it = 0; it < 32; ++it) {
        __syncthreads();              // protect wred/wcnt overwrite
        float sj[4], cj[4];
#pragma unroll
        for (int j = 0; j < 4; ++j) {
            float s = 0.f, cn = 0.f;
#pragma unroll
            for (int nf = 0; nf < 16; ++nf) {
                const float v = acc[nf][j];
                if (v > tau[j]) { s += v; cn += 1.f; }
            }
#pragma unroll
            for (int d = 1; d <= 8; d <<= 1) {
                s  += __shfl_xor(s, d);
                cn += __shfl_xor(cn, d);
            }
            sj[j] = s; cj[j] = cn;
        }
        if (c == 0) {
#pragma unroll
            for (int j = 0; j < 4; ++j) {
                wred[w][g * 4 + j] = sj[j];
                wcnt[w][g * 4 + j] = cj[j];
            }
        }
        __syncthreads();
        int changed = 0;
#pragma unroll
        for (int j = 0; j < 4; ++j) {
            float S = 0.f, C = 0.f;
#pragma unroll
            for (int ww = 0; ww < 8; ++ww) {
                S += wred[ww][g * 4 + j];
                C += wcnt[ww][g * 4 + j];
            }
            tau[j] = (S - 1.0f) / C;
            const int Ci = (int)C;
            changed |= (Ci != cprev[j]);
            cprev[j] = Ci;
        }
        // every wave touches all 16 rows -> wave-level OR == block-level OR
        if (!__any(changed)) break;
    }

    // ---- compact sparse support (ballot + popc), overflow -> atomics ----
    int cnt[4] = {0, 0, 0, 0};
#pragma unroll
    for (int nf = 0; nf < 16; ++nf) {
#pragma unroll
        for (int j = 0; j < 4; ++j) {
            const float p  = acc[nf][j] - tau[j];
            const bool  on = p > 0.f;
            const unsigned long long mask = __ballot(on);
            const unsigned sub = (unsigned)((mask >> (g * 16)) & 0xFFFFull);
            const int pre = __popc(sub & ((1u << c) - 1u));
            const int pos = cnt[j] + pre;
            const int r   = g * 4 + j;
            const int col = n0base + nf * 16 + c;
            if (on) {
                if (pos < CAP) {
                    jlist[r][w][pos] = (unsigned short)col;
                    plist[r][w][pos] = p;
                } else {
                    for (int d = 0; d < 64; ++d)
                        atomicAdd(&O_lds[r][d], p * vb[(size_t)col * 64 + d]);
                }
            }
            cnt[j] += __popc(sub);
        }
    }
    if (c == 0) {
#pragma unroll
        for (int j = 0; j < 4; ++j)
            lcnt[g * 4 + j][w] = (short)min(cnt[j], CAP);
    }
    __syncthreads();

    // ---- sparse PV: wave w -> rows 2w, 2w+1; lane = d ----
    float oacc[2] = {0.f, 0.f};
#pragma unroll
    for (int rr = 0; rr < 2; ++rr) {
        const int r = w * 2 + rr;
#pragma unroll 1
        for (int sw = 0; sw < 8; ++sw) {
            const int n = lcnt[r][sw];
#pragma unroll 1
            for (int e = 0; e < n; ++e) {
                const float p = plist[r][sw][e];
                const int   j = jlist[r][sw][e];
                oacc[rr] += p * vb[(size_t)j * 64 + l];
            }
        }
    }
    const int b = bh >> 3, h = bh & 7;
#pragma unroll
    for (int rr = 0; rr < 2; ++rr) {
        const int r = w * 2 + rr;
        const int i = q0 + r;
        ao[(size_t)(i * BATCH + b) * EMB + h * 64 + l] = oacc[rr] + O_lds[r][l];
    }
}

// =====================================================================
// GEMM2: attn_out(4096x512) @ out_proj_weight(512x512)^T + bias -> d_out
// grid (32, 8)  block 256
// =====================================================================
__global__ __launch_bounds__(256) void gemm_out_proj(
    const float* __restrict__ X, const float* __restrict__ W,
    const float* __restrict__ bias, float* __restrict__ out)
{
    const int t0 = blockIdx.x * 128;
    const int o0 = blockIdx.y * 64;

    __shared__ float Xs[16][132];
    __shared__ float Ws[16][68];

    const int tid = threadIdx.x;
    const int tx  = tid & 15;
    const int ty  = tid >> 4;

    float acc[8][4];
#pragma unroll
    for (int i = 0; i < 8; ++i)
#pragma unroll
        for (int j = 0; j < 4; ++j) acc[i][j] = 0.f;

    for (int ck = 0; ck < 32; ++ck) {
        const int c0 = ck * 16;
#pragma unroll
        for (int p = 0; p < 2; ++p) {
            int f  = tid + p * 256;
            int tl = f >> 2, cq = (f & 3) << 2;
            const float4 v = *(const float4*)&X[(size_t)(t0 + tl) * EMB + c0 + cq];
            Xs[cq + 0][tl] = v.x; Xs[cq + 1][tl] = v.y;
            Xs[cq + 2][tl] = v.z; Xs[cq + 3][tl] = v.w;
        }
        {
            int f  = tid;
            int ol = f >> 2, cq = (f & 3) << 2;
            const float4 v = *(const float4*)&W[(size_t)(o0 + ol) * EMB + c0 + cq];
            Ws[cq + 0][ol] = v.x; Ws[cq + 1][ol] = v.y;
            Ws[cq + 2][ol] = v.z; Ws[cq + 3][ol] = v.w;
        }
        __syncthreads();
#pragma unroll
        for (int cc = 0; cc < 16; ++cc) {
            const float4 a0 = *(const float4*)&Xs[cc][ty * 8];
            const float4 a1 = *(const float4*)&Xs[cc][ty * 8 + 4];
            const float4 b  = *(const float4*)&Ws[cc][tx * 4];
            const float av[8] = {a0.x, a0.y, a0.z, a0.w, a1.x, a1.y, a1.z, a1.w};
            const float bv[4] = {b.x, b.y, b.z, b.w};
#pragma unroll
            for (int i = 0; i < 8; ++i)
#pragma unroll
                for (int j = 0; j < 4; ++j) acc[i][j] += av[i] * bv[j];
        }
        __syncthreads();
    }

    const float b0 = bias[o0 + tx * 4 + 0];
    const float b1 = bias[o0 + tx * 4 + 1];
    const float b2 = bias[o0 + tx * 4 + 2];
    const float b3 = bias[o0 + tx * 4 + 3];
#pragma unroll
    for (int i = 0; i < 8; ++i) {
        float4 o;
        o.x = acc[i][0] + b0; o.y = acc[i][1] + b1;
        o.z = acc[i][2] + b2; o.w = acc[i][3] + b3;
        *(float4*)&out[(size_t)(t0 + ty * 8 + i) * EMB + o0 + tx * 4] = o;
    }
}

// =====================================================================
extern "C" void kernel_launch(void* const* d_in, const int* in_sizes, int n_in,
                              void* d_out, int out_size, void* d_ws, size_t ws_size,
                              hipStream_t stream)
{
    const float* query = (const float*)d_in[0];
    const float* key_  = (const float*)d_in[1];
    const float* value = (const float*)d_in[2];
    const float* ipw   = (const float*)d_in[3];
    const float* ipb   = (const float*)d_in[4];
    const float* opw   = (const float*)d_in[5];
    const float* opb   = (const float*)d_in[6];
    // d_in[7] = update_steps_max (0) -> single attention pass

    char* ws = (char*)d_ws;
    const size_t NTOK = (size_t)BATCH * NH * SEQ * 64;   // 2,097,152 elems
    unsigned short* qhi = (unsigned short*)(ws);                    //  4 MB
    unsigned short* qlo = (unsigned short*)(ws + 4  * 1024 * 1024); //  4 MB
    unsigned short* khi = (unsigned short*)(ws + 8  * 1024 * 1024); //  4 MB
    unsigned short* klo = (unsigned short*)(ws + 12 * 1024 * 1024); //  4 MB
    float*          vnp = (float*)(ws + 16 * 1024 * 1024);          //  8 MB
    float*          aop = (float*)(ws + 24 * 1024 * 1024);          //  8 MB
    (void)NTOK; (void)ws_size;
    float* out = (float*)d_out;

    gemm_qkv_ln<<<dim3(32, 8, 3), 256, 0, stream>>>(
        query, key_, value, ipw, ipb, qhi, qlo, khi, klo, vnp);
    attn_sparsemax_mfma<<<dim3(SEQ / 16, BATCH * NH), 512, 0, stream>>>(
        qhi, qlo, khi, klo, vnp, aop);
    gemm_out_proj<<<dim3(32, 8), 256, 0, stream>>>(aop, opw, opb, out);
}